// Round 1
// baseline (319.254 us; speedup 1.0000x reference)
//
#include <hip/hip_runtime.h>
#include <stdint.h>

typedef unsigned short u16;
typedef __bf16 bf16x8 __attribute__((ext_vector_type(8)));
typedef float f32x4 __attribute__((ext_vector_type(4)));

#define BB 2
#define TT 2048
#define CC 768
#define HH 12
#define HD 64
#define MTOT (BB*TT)   // 4096

__device__ __forceinline__ u16 f2bf(float f) {
    uint32_t u = __builtin_bit_cast(uint32_t, f);
    u = (u + 0x7fffu + ((u >> 16) & 1u)) >> 16;
    return (u16)u;
}
__device__ __forceinline__ float bf2f(u16 h) {
    return __builtin_bit_cast(float, (uint32_t)h << 16);
}

union U16x8 { uint4 v; u16 s[8]; };
union BFrag { bf16x8 b; u16 s[8]; };

// ---------------- fp32 -> bf16 conversion (4 elems/thread) ----------------
__global__ void k_cvt(const float* __restrict__ src, u16* __restrict__ dst, int n4) {
    int i = blockIdx.x * blockDim.x + threadIdx.x;
    if (i >= n4) return;
    float4 v = reinterpret_cast<const float4*>(src)[i];
    uint lo = (uint)f2bf(v.x) | ((uint)f2bf(v.y) << 16);
    uint hi = (uint)f2bf(v.z) | ((uint)f2bf(v.w) << 16);
    reinterpret_cast<uint2*>(dst)[i] = make_uint2(lo, hi);
}

// ---------------- mask -> additive bias ----------------
__global__ void k_mask(const int* __restrict__ m, float* __restrict__ o, int n) {
    int i = blockIdx.x * blockDim.x + threadIdx.x;
    if (i < n) o[i] = (m[i] == 0) ? -1e30f : 0.0f;
}

// ---------------- GEMM: C = A @ W^T + bias ----------------
// A: [M][K] bf16, W: [N][K] bf16. Out: either bf16 head-layout [B][H][T][HD]
// (outLin==null) or fp32 linear [M][N] (outLin!=null).
#define GBM 128
#define GBN 128
#define GBK 32
#define KLD (GBK + 8)   // padded LDS leading dim (80B rows, 16B aligned)

__global__ __launch_bounds__(256)
void k_gemm(const u16* __restrict__ A, const u16* __restrict__ W,
            const float* __restrict__ bias,
            u16* __restrict__ outHead, float* __restrict__ outLin,
            int M, int N, int K)
{
    __shared__ alignas(16) u16 As[GBM][KLD];
    __shared__ alignas(16) u16 Bs[GBN][KLD];

    const int tid  = threadIdx.x;
    const int lane = tid & 63;
    const int wave = tid >> 6;
    const int m0 = blockIdx.y * GBM;
    const int n0 = blockIdx.x * GBN;
    const int wm = (wave >> 1) * 64;
    const int wn = (wave & 1) * 64;

    f32x4 acc[4][4];
#pragma unroll
    for (int m = 0; m < 4; ++m)
#pragma unroll
        for (int n = 0; n < 4; ++n)
            acc[m][n] = f32x4{0.f, 0.f, 0.f, 0.f};

    const int srow = tid >> 2;          // 0..63
    const int scol = (tid & 3) * 8;     // 0,8,16,24

    for (int k0 = 0; k0 < K; k0 += GBK) {
        __syncthreads();   // previous tile's reads complete
        {
            const u16* ga = A + (size_t)(m0 + srow) * K + k0 + scol;
            *reinterpret_cast<uint4*>(&As[srow][scol]) = *reinterpret_cast<const uint4*>(ga);
            *reinterpret_cast<uint4*>(&As[srow + 64][scol]) =
                *reinterpret_cast<const uint4*>(ga + (size_t)64 * K);
            const u16* gb = W + (size_t)(n0 + srow) * K + k0 + scol;
            *reinterpret_cast<uint4*>(&Bs[srow][scol]) = *reinterpret_cast<const uint4*>(gb);
            *reinterpret_cast<uint4*>(&Bs[srow + 64][scol]) =
                *reinterpret_cast<const uint4*>(gb + (size_t)64 * K);
        }
        __syncthreads();

        bf16x8 af[4], bfb[4];
#pragma unroll
        for (int m = 0; m < 4; ++m)
            af[m] = *reinterpret_cast<const bf16x8*>(&As[wm + m * 16 + (lane & 15)][(lane >> 4) * 8]);
#pragma unroll
        for (int n = 0; n < 4; ++n)
            bfb[n] = *reinterpret_cast<const bf16x8*>(&Bs[wn + n * 16 + (lane & 15)][(lane >> 4) * 8]);
#pragma unroll
        for (int m = 0; m < 4; ++m)
#pragma unroll
            for (int n = 0; n < 4; ++n)
                acc[m][n] = __builtin_amdgcn_mfma_f32_16x16x32_bf16(af[m], bfb[n], acc[m][n], 0, 0, 0);
    }

    const int col   = lane & 15;
    const int rbase = (lane >> 4) * 4;
#pragma unroll
    for (int m = 0; m < 4; ++m) {
#pragma unroll
        for (int n = 0; n < 4; ++n) {
            const int gn = n0 + wn + n * 16 + col;
            const float bv = bias[gn];
#pragma unroll
            for (int j = 0; j < 4; ++j) {
                const int gm = m0 + wm + m * 16 + rbase + j;
                const float val = acc[m][n][j] + bv;
                if (outLin) {
                    outLin[(size_t)gm * N + gn] = val;
                } else {
                    const int h = gn >> 6, hd = gn & 63;
                    const int b = gm >> 11, t = gm & (TT - 1);
                    outHead[((size_t)(b * HH + h) * TT + t) * HD + hd] = f2bf(val);
                }
            }
        }
    }
}

// ---------------- flash attention ----------------
// grid: (TT/64, BB*HH). 4 waves/block, 16 queries/wave, 64-key tiles.
__global__ __launch_bounds__(256)
void k_attn(const u16* __restrict__ Qh, const u16* __restrict__ Kh,
            const u16* __restrict__ Vh, const float* __restrict__ maskb,
            u16* __restrict__ Y)
{
    __shared__ alignas(16) u16 Ks[64][72];
    __shared__ alignas(16) u16 Vt[64][72];   // transposed: Vt[hd][key]
    __shared__ alignas(16) u16 Ps[4][16][72];
    __shared__ float mb[64];

    const int tid  = threadIdx.x;
    const int lane = tid & 63;
    const int wave = tid >> 6;
    const int bh = blockIdx.y;
    const int b  = bh / HH;
    const int h  = bh % HH;
    const int q0 = blockIdx.x * 64 + wave * 16;

    const u16* Qp = Qh + (size_t)bh * TT * HD;
    const u16* Kp = Kh + (size_t)bh * TT * HD;
    const u16* Vp = Vh + (size_t)bh * TT * HD;

    // Q fragments, pre-scaled by 1/sqrt(64)=0.125 (exact in bf16)
    bf16x8 qf[2];
    {
        const int r = q0 + (lane & 15);
#pragma unroll
        for (int ks = 0; ks < 2; ++ks) {
            U16x8 t;
            t.v = *reinterpret_cast<const uint4*>(Qp + (size_t)r * HD + ks * 32 + (lane >> 4) * 8);
            BFrag o;
#pragma unroll
            for (int j = 0; j < 8; ++j) o.s[j] = f2bf(bf2f(t.s[j]) * 0.125f);
            qf[ks] = o.b;
        }
    }

    f32x4 oacc[4];
#pragma unroll
    for (int n = 0; n < 4; ++n) oacc[n] = f32x4{0.f, 0.f, 0.f, 0.f};
    float mrun[4], lrun[4];
#pragma unroll
    for (int j = 0; j < 4; ++j) { mrun[j] = -1e30f; lrun[j] = 0.f; }

    const int srow = tid >> 3;         // 0..31
    const int scol = (tid & 7) * 8;    // 0..56

    for (int kt = 0; kt < TT; kt += 64) {
        __syncthreads();
        // stage K rows + V transposed + mask tile
#pragma unroll
        for (int i = 0; i < 2; ++i) {
            const int r = srow + i * 32;
            *reinterpret_cast<uint4*>(&Ks[r][scol]) =
                *reinterpret_cast<const uint4*>(Kp + (size_t)(kt + r) * HD + scol);
            U16x8 t;
            t.v = *reinterpret_cast<const uint4*>(Vp + (size_t)(kt + r) * HD + scol);
#pragma unroll
            for (int j = 0; j < 8; ++j) Vt[scol + j][r] = t.s[j];
        }
        if (tid < 64) mb[tid] = maskb[b * TT + kt + tid];
        __syncthreads();

        // S = (Q*0.125) @ K^T  -> per-lane: S[row=(lane>>4)*4+j][key=n*16+(lane&15)]
        f32x4 sacc[4];
#pragma unroll
        for (int n = 0; n < 4; ++n) sacc[n] = f32x4{0.f, 0.f, 0.f, 0.f};
#pragma unroll
        for (int ks = 0; ks < 2; ++ks)
#pragma unroll
            for (int n = 0; n < 4; ++n) {
                bf16x8 kf = *reinterpret_cast<const bf16x8*>(
                    &Ks[n * 16 + (lane & 15)][ks * 32 + (lane >> 4) * 8]);
                sacc[n] = __builtin_amdgcn_mfma_f32_16x16x32_bf16(qf[ks], kf, sacc[n], 0, 0, 0);
            }

        // online softmax
        float p[4][4], tmax[4];
#pragma unroll
        for (int j = 0; j < 4; ++j) tmax[j] = -1e30f;
        float mbv[4];
#pragma unroll
        for (int n = 0; n < 4; ++n) mbv[n] = mb[n * 16 + (lane & 15)];
#pragma unroll
        for (int n = 0; n < 4; ++n)
#pragma unroll
            for (int j = 0; j < 4; ++j) {
                float s = sacc[n][j] + mbv[n];
                p[n][j] = s;
                tmax[j] = fmaxf(tmax[j], s);
            }
#pragma unroll
        for (int off = 1; off < 16; off <<= 1)
#pragma unroll
            for (int j = 0; j < 4; ++j) tmax[j] = fmaxf(tmax[j], __shfl_xor(tmax[j], off));
        float scl[4];
#pragma unroll
        for (int j = 0; j < 4; ++j) {
            float mnew = fmaxf(mrun[j], tmax[j]);
            scl[j] = __expf(mrun[j] - mnew);
            mrun[j] = mnew;
        }
#pragma unroll
        for (int n = 0; n < 4; ++n)
#pragma unroll
            for (int j = 0; j < 4; ++j) {
                float s = p[n][j];
                p[n][j] = (s < -1e29f) ? 0.f : __expf(s - mrun[j]);
            }
#pragma unroll
        for (int j = 0; j < 4; ++j) {
            float s = p[0][j] + p[1][j] + p[2][j] + p[3][j];
#pragma unroll
            for (int off = 1; off < 16; off <<= 1) s += __shfl_xor(s, off);
            lrun[j] = lrun[j] * scl[j] + s;
        }

        // P -> LDS (per-wave), as MFMA A-fragments source
#pragma unroll
        for (int n = 0; n < 4; ++n)
#pragma unroll
            for (int j = 0; j < 4; ++j)
                Ps[wave][(lane >> 4) * 4 + j][n * 16 + (lane & 15)] = f2bf(p[n][j]);

        // O = O*scl + P @ V
#pragma unroll
        for (int n = 0; n < 4; ++n)
#pragma unroll
            for (int j = 0; j < 4; ++j) oacc[n][j] *= scl[j];
#pragma unroll
        for (int ks = 0; ks < 2; ++ks) {
            bf16x8 pf = *reinterpret_cast<const bf16x8*>(
                &Ps[wave][lane & 15][ks * 32 + (lane >> 4) * 8]);
#pragma unroll
            for (int n = 0; n < 4; ++n) {
                bf16x8 vf = *reinterpret_cast<const bf16x8*>(
                    &Vt[n * 16 + (lane & 15)][ks * 32 + (lane >> 4) * 8]);
                oacc[n] = __builtin_amdgcn_mfma_f32_16x16x32_bf16(pf, vf, oacc[n], 0, 0, 0);
            }
        }
    }

    // epilogue: y[b][t][h*64+hd] = O/l   (bf16)
#pragma unroll
    for (int n = 0; n < 4; ++n)
#pragma unroll
        for (int j = 0; j < 4; ++j) {
            const int t = q0 + (lane >> 4) * 4 + j;
            const int c = h * 64 + n * 16 + (lane & 15);
            Y[((size_t)b * TT + t) * CC + c] = f2bf(oacc[n][j] / lrun[j]);
        }
}

// ---------------- launcher ----------------
extern "C" void kernel_launch(void* const* d_in, const int* in_sizes, int n_in,
                              void* d_out, int out_size, void* d_ws, size_t ws_size,
                              hipStream_t stream)
{
    const float* x    = (const float*)d_in[0];
    const int*   mask = (const int*)d_in[1];
    const float* Wq   = (const float*)d_in[2];
    const float* bq   = (const float*)d_in[3];
    const float* Wk   = (const float*)d_in[4];
    const float* bk   = (const float*)d_in[5];
    const float* Wv   = (const float*)d_in[6];
    const float* bv   = (const float*)d_in[7];
    const float* Wp   = (const float*)d_in[8];
    const float* bp   = (const float*)d_in[9];
    float* out = (float*)d_out;

    char* w = (char*)d_ws;
    auto alloc = [&](size_t bytes) {
        char* p = w;
        w += (bytes + 255) & ~(size_t)255;
        return p;
    };
    u16* x_bf  = (u16*)alloc((size_t)MTOT * CC * 2);
    u16* wq_bf = (u16*)alloc((size_t)CC * CC * 2);
    u16* wk_bf = (u16*)alloc((size_t)CC * CC * 2);
    u16* wv_bf = (u16*)alloc((size_t)CC * CC * 2);
    u16* wp_bf = (u16*)alloc((size_t)CC * CC * 2);
    u16* qh    = (u16*)alloc((size_t)MTOT * CC * 2);
    u16* kh    = (u16*)alloc((size_t)MTOT * CC * 2);
    u16* vh    = (u16*)alloc((size_t)MTOT * CC * 2);
    u16* y_bf  = (u16*)alloc((size_t)MTOT * CC * 2);
    float* maskb = (float*)alloc((size_t)BB * TT * 4);

    const int NX4 = MTOT * CC / 4;
    k_cvt<<<(NX4 + 255) / 256, 256, 0, stream>>>(x, x_bf, NX4);
    const int NW4 = CC * CC / 4;
    k_cvt<<<(NW4 + 255) / 256, 256, 0, stream>>>(Wq, wq_bf, NW4);
    k_cvt<<<(NW4 + 255) / 256, 256, 0, stream>>>(Wk, wk_bf, NW4);
    k_cvt<<<(NW4 + 255) / 256, 256, 0, stream>>>(Wv, wv_bf, NW4);
    k_cvt<<<(NW4 + 255) / 256, 256, 0, stream>>>(Wp, wp_bf, NW4);
    k_mask<<<(BB * TT + 255) / 256, 256, 0, stream>>>(mask, maskb, BB * TT);

    dim3 gg(CC / GBN, MTOT / GBM);  // (6, 32)
    k_gemm<<<gg, 256, 0, stream>>>(x_bf, wq_bf, bq, qh, nullptr, MTOT, CC, CC);
    k_gemm<<<gg, 256, 0, stream>>>(x_bf, wk_bf, bk, kh, nullptr, MTOT, CC, CC);
    k_gemm<<<gg, 256, 0, stream>>>(x_bf, wv_bf, bv, vh, nullptr, MTOT, CC, CC);

    k_attn<<<dim3(TT / 64, BB * HH), 256, 0, stream>>>(qh, kh, vh, maskb, y_bf);

    k_gemm<<<gg, 256, 0, stream>>>(y_bf, wp_bf, bp, nullptr, out, MTOT, CC, CC);
}

// Round 3
// 268.450 us; speedup vs baseline: 1.1892x; 1.1892x over previous
//
#include <hip/hip_runtime.h>
#include <stdint.h>

typedef unsigned short u16;
typedef __bf16 bf16x8 __attribute__((ext_vector_type(8)));
typedef float f32x4 __attribute__((ext_vector_type(4)));

#define BB 2
#define TT 2048
#define CC 768
#define HH 12
#define HD 64
#define MTOT (BB*TT)   // 4096
#define N_QKV (3*CC)   // 2304

__device__ __forceinline__ u16 f2bf(float f) {
    uint32_t u = __builtin_bit_cast(uint32_t, f);
    u = (u + 0x7fffu + ((u >> 16) & 1u)) >> 16;
    return (u16)u;
}
__device__ __forceinline__ float bf2f(u16 h) {
    return __builtin_bit_cast(float, (uint32_t)h << 16);
}

union U16x8 { uint4 v; u16 s[8]; };

__device__ __forceinline__ void gl_lds16(const u16* g, u16* l) {
    __builtin_amdgcn_global_load_lds(
        (const __attribute__((address_space(1))) uint32_t*)g,
        (__attribute__((address_space(3))) uint32_t*)l, 16, 0, 0);
}

// ---------------- fp32 -> bf16 conversion (4 elems/thread) ----------------
__global__ void k_cvt(const float* __restrict__ src, u16* __restrict__ dst, int n4) {
    int i = blockIdx.x * blockDim.x + threadIdx.x;
    if (i >= n4) return;
    float4 v = reinterpret_cast<const float4*>(src)[i];
    uint lo = (uint)f2bf(v.x) | ((uint)f2bf(v.y) << 16);
    uint hi = (uint)f2bf(v.z) | ((uint)f2bf(v.w) << 16);
    reinterpret_cast<uint2*>(dst)[i] = make_uint2(lo, hi);
}

// ---------------- mask -> additive bias ----------------
__global__ void k_mask(const int* __restrict__ m, float* __restrict__ o, int n) {
    int i = blockIdx.x * blockDim.x + threadIdx.x;
    if (i < n) o[i] = (m[i] == 0) ? -1e30f : 0.0f;
}

// ---------------- pack biases bq|bk|bv -> bqkv[2304] ----------------
__global__ void k_packb(const float* __restrict__ bq, const float* __restrict__ bk,
                        const float* __restrict__ bv, float* __restrict__ o) {
    int i = blockIdx.x * blockDim.x + threadIdx.x;
    if (i < CC) o[i] = bq[i];
    else if (i < 2 * CC) o[i] = bk[i - CC];
    else if (i < 3 * CC) o[i] = bv[i - 2 * CC];
}

// ---------------- GEMM: C = A @ W^T + bias (m97-style staging) ----------------
// mode 0: N=2304, epilogue routes q -> [B,H,T,HD], k -> [B,H,T,HD], v -> [B,H,HD,T] (bf16)
// mode 1: N=768, fp32 linear out
#define GBM 128
#define GBN 128
#define GBK 32

__global__ __launch_bounds__(256)
void k_gemm(const u16* __restrict__ A, const u16* __restrict__ W,
            const float* __restrict__ bias, int K, int N, int mode,
            u16* __restrict__ outQ, u16* __restrict__ outK, u16* __restrict__ outVt,
            float* __restrict__ outLin)
{
    __shared__ alignas(16) u16 As[GBM][GBK];
    __shared__ alignas(16) u16 Bs[GBN][GBK];

    const int tid  = threadIdx.x;
    const int lane = tid & 63;
    const int wave = tid >> 6;
    const int m0 = blockIdx.y * GBM;
    const int n0 = blockIdx.x * GBN;
    const int wm = (wave >> 1) * 64;
    const int wn = (wave & 1) * 64;

    f32x4 acc[4][4];
#pragma unroll
    for (int m = 0; m < 4; ++m)
#pragma unroll
        for (int n = 0; n < 4; ++n)
            acc[m][n] = f32x4{0.f, 0.f, 0.f, 0.f};

    const int lrow = lane >> 2;        // 0..15 within a 16-row chunk
    const int lcol = (lane & 3) * 8;   // 0,8,16,24

    for (int k0 = 0; k0 < K; k0 += GBK) {
        __syncthreads();   // previous tile's frag reads complete
        {
            const int r0 = wave * 32;
            gl_lds16(A + (size_t)(m0 + r0 + lrow) * K + k0 + lcol,      &As[r0][0]);
            gl_lds16(A + (size_t)(m0 + r0 + 16 + lrow) * K + k0 + lcol, &As[r0 + 16][0]);
            gl_lds16(W + (size_t)(n0 + r0 + lrow) * K + k0 + lcol,      &Bs[r0][0]);
            gl_lds16(W + (size_t)(n0 + r0 + 16 + lrow) * K + k0 + lcol, &Bs[r0 + 16][0]);
        }
        __syncthreads();   // drains vmcnt -> LDS ready

        bf16x8 af[4], bfb[4];
#pragma unroll
        for (int m = 0; m < 4; ++m)
            af[m] = *reinterpret_cast<const bf16x8*>(&As[wm + m * 16 + (lane & 15)][(lane >> 4) * 8]);
#pragma unroll
        for (int n = 0; n < 4; ++n)
            bfb[n] = *reinterpret_cast<const bf16x8*>(&Bs[wn + n * 16 + (lane & 15)][(lane >> 4) * 8]);
#pragma unroll
        for (int m = 0; m < 4; ++m)
#pragma unroll
            for (int n = 0; n < 4; ++n)
                acc[m][n] = __builtin_amdgcn_mfma_f32_16x16x32_bf16(af[m], bfb[n], acc[m][n], 0, 0, 0);
    }

    const int col   = lane & 15;
    const int rbase = (lane >> 4) * 4;
#pragma unroll
    for (int m = 0; m < 4; ++m) {
#pragma unroll
        for (int n = 0; n < 4; ++n) {
            const int gn = n0 + wn + n * 16 + col;
            const float bv = bias[gn];
#pragma unroll
            for (int j = 0; j < 4; ++j) {
                const int gm = m0 + wm + m * 16 + rbase + j;
                const float val = acc[m][n][j] + bv;
                if (mode == 1) {
                    outLin[(size_t)gm * N + gn] = val;
                } else {
                    const int proj = gn / CC;           // 0=q,1=k,2=v
                    const int c = gn - proj * CC;
                    const int h = c >> 6, hd = c & 63;
                    const int b = gm >> 11, t = gm & (TT - 1);
                    if (proj == 0)
                        outQ[((size_t)(b * HH + h) * TT + t) * HD + hd] = f2bf(val);
                    else if (proj == 1)
                        outK[((size_t)(b * HH + h) * TT + t) * HD + hd] = f2bf(val);
                    else
                        outVt[((size_t)(b * HH + h) * HD + hd) * TT + t] = f2bf(val);
                }
            }
        }
    }
}

// ---------------- flash attention, barrier-free ----------------
// grid: 1536 blocks x 64 threads. 1 wave/block, 32 queries/wave, 128-key tiles.
// K read row-major from L2; V read from pre-transposed [B,H,HD,T]. No K/V LDS staging.
__global__ __launch_bounds__(64)
void k_attn(const u16* __restrict__ Qh, const u16* __restrict__ Kh,
            const u16* __restrict__ Vt, const float* __restrict__ maskb,
            u16* __restrict__ Y)
{
    __shared__ alignas(16) u16 Ps[32][136];   // row stride 272B -> <=2-way conflicts

    const int lane = threadIdx.x;
    // XCD-chunked swizzle: 1536 blocks, 192 consecutive virtual blocks per XCD (3 heads)
    const int raw  = blockIdx.x;
    const int virt = (raw & 7) * 192 + (raw >> 3);
    const int bh = virt >> 6;
    const int b  = bh / HH, h = bh % HH;
    const int q0 = (virt & 63) * 32;

    const u16* Qp = Qh + (size_t)bh * TT * HD;
    const u16* Kp = Kh + (size_t)bh * TT * HD;
    const u16* Vp = Vt + (size_t)bh * HD * TT;
    const float* mrow = maskb + b * TT;

    const int l15 = lane & 15;
    const int lg  = lane >> 4;        // 0..3

    // Q fragments, pre-scaled by 1/sqrt(64)=0.125
    bf16x8 qf[2][2];
#pragma unroll
    for (int m = 0; m < 2; ++m)
#pragma unroll
        for (int ks = 0; ks < 2; ++ks) {
            U16x8 t;
            t.v = *reinterpret_cast<const uint4*>(
                Qp + (size_t)(q0 + m * 16 + l15) * HD + ks * 32 + lg * 8);
            U16x8 o;
#pragma unroll
            for (int j = 0; j < 8; ++j) o.s[j] = f2bf(bf2f(t.s[j]) * 0.125f);
            qf[m][ks] = __builtin_bit_cast(bf16x8, o.v);
        }

    f32x4 oacc[2][4];
#pragma unroll
    for (int m = 0; m < 2; ++m)
#pragma unroll
        for (int n = 0; n < 4; ++n) oacc[m][n] = f32x4{0.f, 0.f, 0.f, 0.f};
    float mrun[2][4], lrun[2][4];
#pragma unroll
    for (int m = 0; m < 2; ++m)
#pragma unroll
        for (int j = 0; j < 4; ++j) { mrun[m][j] = -1e30f; lrun[m][j] = 0.f; }

    for (int kt = 0; kt < TT; kt += 128) {
        // ---- S = (Q*0.125) @ K^T   (32q x 128k) ----
        f32x4 sacc[2][8];
#pragma unroll
        for (int m = 0; m < 2; ++m)
#pragma unroll
            for (int n = 0; n < 8; ++n) sacc[m][n] = f32x4{0.f, 0.f, 0.f, 0.f};
#pragma unroll
        for (int ks = 0; ks < 2; ++ks) {
            uint4 kfr[8];
#pragma unroll
            for (int n = 0; n < 8; ++n)
                kfr[n] = *reinterpret_cast<const uint4*>(
                    Kp + (size_t)(kt + n * 16 + l15) * HD + ks * 32 + lg * 8);
#pragma unroll
            for (int n = 0; n < 8; ++n) {
                bf16x8 kf = __builtin_bit_cast(bf16x8, kfr[n]);
#pragma unroll
                for (int m = 0; m < 2; ++m)
                    sacc[m][n] = __builtin_amdgcn_mfma_f32_16x16x32_bf16(qf[m][ks], kf, sacc[m][n], 0, 0, 0);
            }
        }

        // ---- online softmax (rows lane-local over n, 16-lane shuffle over keys) ----
        float mbv[8];
#pragma unroll
        for (int n = 0; n < 8; ++n) mbv[n] = mrow[kt + n * 16 + l15];

        float tmax[2][4];
#pragma unroll
        for (int m = 0; m < 2; ++m)
#pragma unroll
            for (int j = 0; j < 4; ++j) tmax[m][j] = -1e30f;
#pragma unroll
        for (int m = 0; m < 2; ++m)
#pragma unroll
            for (int n = 0; n < 8; ++n)
#pragma unroll
                for (int j = 0; j < 4; ++j) {
                    float s = sacc[m][n][j] + mbv[n];
                    sacc[m][n][j] = s;
                    tmax[m][j] = fmaxf(tmax[m][j], s);
                }
#pragma unroll
        for (int off = 1; off < 16; off <<= 1)
#pragma unroll
            for (int m = 0; m < 2; ++m)
#pragma unroll
                for (int j = 0; j < 4; ++j)
                    tmax[m][j] = fmaxf(tmax[m][j], __shfl_xor(tmax[m][j], off));

        float scl[2][4];
#pragma unroll
        for (int m = 0; m < 2; ++m)
#pragma unroll
            for (int j = 0; j < 4; ++j) {
                float mnew = fmaxf(mrun[m][j], tmax[m][j]);
                scl[m][j] = __expf(mrun[m][j] - mnew);
                mrun[m][j] = mnew;
            }

        float rs[2][4];
#pragma unroll
        for (int m = 0; m < 2; ++m)
#pragma unroll
            for (int j = 0; j < 4; ++j) rs[m][j] = 0.f;
#pragma unroll
        for (int m = 0; m < 2; ++m)
#pragma unroll
            for (int n = 0; n < 8; ++n)
#pragma unroll
                for (int j = 0; j < 4; ++j) {
                    float s = sacc[m][n][j];
                    float p = (s < -1e29f) ? 0.f : __expf(s - mrun[m][j]);
                    sacc[m][n][j] = p;
                    rs[m][j] += p;
                }
#pragma unroll
        for (int off = 1; off < 16; off <<= 1)
#pragma unroll
            for (int m = 0; m < 2; ++m)
#pragma unroll
                for (int j = 0; j < 4; ++j) rs[m][j] += __shfl_xor(rs[m][j], off);
#pragma unroll
        for (int m = 0; m < 2; ++m)
#pragma unroll
            for (int j = 0; j < 4; ++j) lrun[m][j] = lrun[m][j] * scl[m][j] + rs[m][j];

        // ---- P -> LDS (per-wave, no barrier needed) ----
#pragma unroll
        for (int m = 0; m < 2; ++m)
#pragma unroll
            for (int n = 0; n < 8; ++n)
#pragma unroll
                for (int j = 0; j < 4; ++j)
                    Ps[m * 16 + lg * 4 + j][n * 16 + l15] = f2bf(sacc[m][n][j]);

        // ---- O = O*scl + P @ V ----
#pragma unroll
        for (int m = 0; m < 2; ++m)
#pragma unroll
            for (int n = 0; n < 4; ++n)
#pragma unroll
                for (int j = 0; j < 4; ++j) oacc[m][n][j] *= scl[m][j];

#pragma unroll
        for (int ks2 = 0; ks2 < 4; ++ks2) {
            bf16x8 pf[2];
#pragma unroll
            for (int m = 0; m < 2; ++m)
                pf[m] = *reinterpret_cast<const bf16x8*>(&Ps[m * 16 + l15][ks2 * 32 + lg * 8]);
            uint4 vfr[4];
#pragma unroll
            for (int n = 0; n < 4; ++n)
                vfr[n] = *reinterpret_cast<const uint4*>(
                    Vp + (size_t)(n * 16 + l15) * TT + kt + ks2 * 32 + lg * 8);
#pragma unroll
            for (int n = 0; n < 4; ++n) {
                bf16x8 vf = __builtin_bit_cast(bf16x8, vfr[n]);
#pragma unroll
                for (int m = 0; m < 2; ++m)
                    oacc[m][n] = __builtin_amdgcn_mfma_f32_16x16x32_bf16(pf[m], vf, oacc[m][n], 0, 0, 0);
            }
        }
    }

    // ---- epilogue: y[b][t][h*64+hd] = O/l (bf16) ----
#pragma unroll
    for (int m = 0; m < 2; ++m)
#pragma unroll
        for (int n = 0; n < 4; ++n)
#pragma unroll
            for (int j = 0; j < 4; ++j) {
                const int t = q0 + m * 16 + lg * 4 + j;
                const int c = h * 64 + n * 16 + l15;
                Y[((size_t)b * TT + t) * CC + c] = f2bf(oacc[m][n][j] / lrun[m][j]);
            }
}

// ---------------- launcher ----------------
extern "C" void kernel_launch(void* const* d_in, const int* in_sizes, int n_in,
                              void* d_out, int out_size, void* d_ws, size_t ws_size,
                              hipStream_t stream)
{
    const float* x    = (const float*)d_in[0];
    const int*   mask = (const int*)d_in[1];
    const float* Wq   = (const float*)d_in[2];
    const float* bq   = (const float*)d_in[3];
    const float* Wk   = (const float*)d_in[4];
    const float* bk   = (const float*)d_in[5];
    const float* Wv   = (const float*)d_in[6];
    const float* bv   = (const float*)d_in[7];
    const float* Wp   = (const float*)d_in[8];
    const float* bp   = (const float*)d_in[9];
    float* out = (float*)d_out;

    char* w = (char*)d_ws;
    auto alloc = [&](size_t bytes) {
        char* p = w;
        w += (bytes + 255) & ~(size_t)255;
        return p;
    };
    u16* x_bf    = (u16*)alloc((size_t)MTOT * CC * 2);
    u16* wqkv_bf = (u16*)alloc((size_t)3 * CC * CC * 2);   // contiguous q|k|v weights
    u16* wp_bf   = (u16*)alloc((size_t)CC * CC * 2);
    u16* qh      = (u16*)alloc((size_t)MTOT * CC * 2);
    u16* kh      = (u16*)alloc((size_t)MTOT * CC * 2);
    u16* vt      = (u16*)alloc((size_t)MTOT * CC * 2);
    u16* y_bf    = (u16*)alloc((size_t)MTOT * CC * 2);
    float* maskb = (float*)alloc((size_t)BB * TT * 4);
    float* bqkv  = (float*)alloc((size_t)N_QKV * 4);

    const int NX4 = MTOT * CC / 4;
    k_cvt<<<(NX4 + 255) / 256, 256, 0, stream>>>(x, x_bf, NX4);
    const int NW4 = CC * CC / 4;
    k_cvt<<<(NW4 + 255) / 256, 256, 0, stream>>>(Wq, wqkv_bf, NW4);
    k_cvt<<<(NW4 + 255) / 256, 256, 0, stream>>>(Wk, wqkv_bf + (size_t)CC * CC, NW4);
    k_cvt<<<(NW4 + 255) / 256, 256, 0, stream>>>(Wv, wqkv_bf + (size_t)2 * CC * CC, NW4);
    k_cvt<<<(NW4 + 255) / 256, 256, 0, stream>>>(Wp, wp_bf, NW4);
    k_mask<<<(BB * TT + 255) / 256, 256, 0, stream>>>(mask, maskb, BB * TT);
    k_packb<<<(N_QKV + 255) / 256, 256, 0, stream>>>(bq, bk, bv, bqkv);

    // fused QKV projection: [4096 x 768] @ [2304 x 768]^T
    k_gemm<<<dim3(N_QKV / GBN, MTOT / GBM), 256, 0, stream>>>(
        x_bf, wqkv_bf, bqkv, CC, N_QKV, 0, qh, kh, vt, nullptr);

    k_attn<<<dim3(1536), 64, 0, stream>>>(qh, kh, vt, maskb, y_bf);

    // output projection: fp32 out
    k_gemm<<<dim3(CC / GBN, MTOT / GBM), 256, 0, stream>>>(
        y_bf, wp_bf, bp, CC, CC, 1, nullptr, nullptr, nullptr, out);
}